// Round 8
// baseline (395.879 us; speedup 1.0000x reference)
//
#include <hip/hip_runtime.h>
#include <math.h>

#define TSEQ 2048
#define DIM  512
#define NB   8
#define BTOT 16384
#define SCALE 0.04419417382415922f

typedef __attribute__((ext_vector_type(8))) short bf16x8;
typedef __attribute__((ext_vector_type(4))) float f32x4;
typedef __attribute__((ext_vector_type(16))) float f32x16;
typedef __attribute__((ext_vector_type(8))) unsigned short u16x8;
typedef __attribute__((ext_vector_type(4))) unsigned short u16x4;
typedef unsigned short ushort_t;

__device__ __forceinline__ unsigned short f2bf(float f) {
    unsigned u = __builtin_bit_cast(unsigned, f);
    u += 0x7FFFu + ((u >> 16) & 1u);
    return (unsigned short)(u >> 16);
}
__device__ __forceinline__ float bf2f(unsigned short h) {
    unsigned u = ((unsigned)h) << 16;
    return __builtin_bit_cast(float, u);
}

// Tiled k-chunk layouts (128 rows x 64 cols = 8192 shorts = 16 KB per tile):
//   P  tile index: (b*16 + it)*32 + kc    (it = i>>7, kc = j>>6)
//   VLT tile index: (b*4 + nt)*32 + kc    (nt = d>>7, kc = t_local>>6)

// ---------------------------------------------------------------------------
// P0: gather embedding rows, split to hi/lo bf16
// ---------------------------------------------------------------------------
__global__ __launch_bounds__(256) void k_split_embed(const int* __restrict__ x,
                                                     const float* __restrict__ embed,
                                                     ushort_t* __restrict__ Ehi,
                                                     ushort_t* __restrict__ Elo) {
    int idx = blockIdx.x * 256 + threadIdx.x;
    int row = idx >> 6;
    int c   = (idx & 63) << 3;
    int tok = x[row];
    const float* src = embed + (size_t)tok * DIM + c;
    float4 v0 = *(const float4*)src;
    float4 v1 = *(const float4*)(src + 4);
    float vv[8] = {v0.x, v0.y, v0.z, v0.w, v1.x, v1.y, v1.z, v1.w};
    u16x8 h, l;
#pragma unroll
    for (int i = 0; i < 8; ++i) {
        unsigned short hh = f2bf(vv[i]);
        h[i] = hh;
        l[i] = f2bf(vv[i] - bf2f(hh));
    }
    *(u16x8*)(Ehi + (size_t)row * DIM + c) = h;
    *(u16x8*)(Elo + (size_t)row * DIM + c) = l;
}

// ---------------------------------------------------------------------------
// P1: fused small fp32 SGEMMs
// ---------------------------------------------------------------------------
__global__ __launch_bounds__(256) void k_wgemm(const float* __restrict__ Wq,
                                               const float* __restrict__ Wk,
                                               const float* __restrict__ lin_w,
                                               const float* __restrict__ Wv,
                                               ushort_t* __restrict__ Gthi,
                                               ushort_t* __restrict__ Gtlo,
                                               ushort_t* __restrict__ Mbf) {
    __shared__ float As[32][33];
    __shared__ float Bs[32][33];
    int tid = threadIdx.x;
    int seg = blockIdx.z;
    int m0 = blockIdx.x * 32;
    int n0 = blockIdx.y * 32;
    int dr = tid >> 3;
    int c4 = (tid & 7) * 4;
    int tx = tid & 15, ty = tid >> 4;

    const float* Bsrc = seg ? Wv : Wq;
    float acc[2][2] = {{0.f, 0.f}, {0.f, 0.f}};

    for (int k0 = 0; k0 < DIM; k0 += 32) {
        float4 a4, b4;
        if (seg == 0) {
            a4 = *(const float4*)(Wk + (size_t)(k0 + dr) * DIM + m0 + c4);
        } else {
            a4 = *(const float4*)(lin_w + (size_t)(m0 + dr) * DIM + k0 + c4);
        }
        b4 = *(const float4*)(Bsrc + (size_t)(k0 + dr) * DIM + n0 + c4);
        __syncthreads();
        if (seg == 0) {
            *(float4*)&As[dr][c4] = a4;
        } else {
            As[c4 + 0][dr] = a4.x; As[c4 + 1][dr] = a4.y;
            As[c4 + 2][dr] = a4.z; As[c4 + 3][dr] = a4.w;
        }
        *(float4*)&Bs[dr][c4] = b4;
        __syncthreads();
#pragma unroll
        for (int k = 0; k < 32; ++k) {
            float a0 = As[k][ty * 2], a1 = As[k][ty * 2 + 1];
            float b0 = Bs[k][tx * 2], b1 = Bs[k][tx * 2 + 1];
            acc[0][0] = fmaf(a0, b0, acc[0][0]);
            acc[0][1] = fmaf(a0, b1, acc[0][1]);
            acc[1][0] = fmaf(a1, b0, acc[1][0]);
            acc[1][1] = fmaf(a1, b1, acc[1][1]);
        }
    }
#pragma unroll
    for (int i = 0; i < 2; ++i)
#pragma unroll
        for (int j = 0; j < 2; ++j) {
            int row = m0 + ty * 2 + i;
            int col = n0 + tx * 2 + j;
            if (seg == 0) {
                float v = acc[i][j] * SCALE;
                unsigned short hh = f2bf(v);
                Gthi[(size_t)row * DIM + col] = hh;
                Gtlo[(size_t)row * DIM + col] = f2bf(v - bf2f(hh));
            } else {
                Mbf[(size_t)row * DIM + col] = f2bf(acc[i][j]);
            }
        }
}

// ---------------------------------------------------------------------------
// K1: H = E . Gt^T  (3-pass split-bf16, 16x16x32).
//     NEW epilogue: LDS-transpose (aliased over staging smem, no LDS growth)
//     + fully coalesced u16x8 stores (256-B dense segments).
// ---------------------------------------------------------------------------
__global__ __launch_bounds__(256) void k_proj_h(const ushort_t* __restrict__ Ehi, const ushort_t* __restrict__ Elo,
                                                const ushort_t* __restrict__ Gthi, const ushort_t* __restrict__ Gtlo,
                                                ushort_t* __restrict__ Hhi, ushort_t* __restrict__ Hlo) {
    __shared__ ushort_t smem[4][128][40];                      // 40 KB staging
    ushort_t (*Ct)[132] = (ushort_t(*)[132])&smem[0][0][0];    // 33.8 KB alias (epilogue only)
    int tid = threadIdx.x;
    int m0 = blockIdx.x * 128;
    int n0 = blockIdx.y * 128;

    int wave = tid >> 6, lane = tid & 63;
    int wm = wave >> 1, wn = wave & 1;
    int q = lane >> 4, l16 = lane & 15;
    int r = tid >> 1, c0 = (tid & 1) << 4;

    const ushort_t* gah = Ehi + (size_t)(m0 + r) * DIM + c0;
    const ushort_t* gal = Elo + (size_t)(m0 + r) * DIM + c0;
    const ushort_t* gbh = Gthi + (size_t)(n0 + r) * DIM + c0;
    const ushort_t* gbl = Gtlo + (size_t)(n0 + r) * DIM + c0;

    const f32x4 fz = {0.f, 0.f, 0.f, 0.f};
    f32x4 acc[4][4];
#pragma unroll
    for (int i = 0; i < 4; ++i)
#pragma unroll
        for (int j = 0; j < 4; ++j) acc[i][j] = fz;

    for (int k0 = 0; k0 < DIM; k0 += 32) {
        u16x8 a0 = *(const u16x8*)(gah + k0);
        u16x8 a1 = *(const u16x8*)(gah + k0 + 8);
        u16x8 a2 = *(const u16x8*)(gal + k0);
        u16x8 a3 = *(const u16x8*)(gal + k0 + 8);
        u16x8 b0 = *(const u16x8*)(gbh + k0);
        u16x8 b1 = *(const u16x8*)(gbh + k0 + 8);
        u16x8 b2 = *(const u16x8*)(gbl + k0);
        u16x8 b3 = *(const u16x8*)(gbl + k0 + 8);
        __syncthreads();
        *(u16x8*)&smem[0][r][c0] = a0; *(u16x8*)&smem[0][r][c0 + 8] = a1;
        *(u16x8*)&smem[1][r][c0] = a2; *(u16x8*)&smem[1][r][c0 + 8] = a3;
        *(u16x8*)&smem[2][r][c0] = b0; *(u16x8*)&smem[2][r][c0 + 8] = b1;
        *(u16x8*)&smem[3][r][c0] = b2; *(u16x8*)&smem[3][r][c0 + 8] = b3;
        __syncthreads();
        bf16x8 fah[4], fal[4], fbh[4], fbl[4];
#pragma unroll
        for (int t = 0; t < 4; ++t) {
            int ar = wm * 64 + t * 16 + l16;
            int br = wn * 64 + t * 16 + l16;
            fah[t] = *(const bf16x8*)&smem[0][ar][q * 8];
            fal[t] = *(const bf16x8*)&smem[1][ar][q * 8];
            fbh[t] = *(const bf16x8*)&smem[2][br][q * 8];
            fbl[t] = *(const bf16x8*)&smem[3][br][q * 8];
        }
#pragma unroll
        for (int i = 0; i < 4; ++i)
#pragma unroll
            for (int j = 0; j < 4; ++j) {
                f32x4 c = acc[i][j];
                c = __builtin_amdgcn_mfma_f32_16x16x32_bf16(fal[i], fbh[j], c, 0, 0, 0);
                c = __builtin_amdgcn_mfma_f32_16x16x32_bf16(fah[i], fbl[j], c, 0, 0, 0);
                c = __builtin_amdgcn_mfma_f32_16x16x32_bf16(fah[i], fbh[j], c, 0, 0, 0);
                acc[i][j] = c;
            }
    }
    // epilogue: two LDS rounds (hi, lo), coalesced 256-B-dense stores
    for (int half = 0; half < 2; ++half) {
        __syncthreads();
#pragma unroll
        for (int i = 0; i < 4; ++i)
#pragma unroll
            for (int j = 0; j < 4; ++j) {
                int col = wn * 64 + j * 16 + l16;
                f32x4 c = acc[i][j];
#pragma unroll
                for (int rr = 0; rr < 4; ++rr) {
                    int row = wm * 64 + i * 16 + q * 4 + rr;
                    float v = c[rr];
                    unsigned short hh = f2bf(v);
                    Ct[row][col] = half ? f2bf(v - bf2f(hh)) : hh;
                }
            }
        __syncthreads();
        ushort_t* O = half ? Hlo : Hhi;
        int lc = (tid & 15) * 8;       // 16 lanes cover 128 shorts (256 B dense)
        int r0 = tid >> 4;             // 16 rows per pass
#pragma unroll
        for (int p = 0; p < 8; ++p) {
            int row = p * 16 + r0;
            *(u16x8*)(O + (size_t)(m0 + row) * DIM + n0 + lc) = *(const u16x8*)&Ct[row][lc];
        }
    }
}

// ---------------------------------------------------------------------------
// K2: VLT tiles = Mbf . Ehi^T (single-pass bf16), TILED output
// ---------------------------------------------------------------------------
__global__ __launch_bounds__(256) void k_proj_vlt(const ushort_t* __restrict__ Mbf,
                                                  const ushort_t* __restrict__ Ehi,
                                                  ushort_t* __restrict__ VLT) {
    __shared__ ushort_t Ah[128][40], Bh[128][40];
    __shared__ ushort_t Ct[128][132];
    int tid = threadIdx.x;
    int nt = blockIdx.x;              // d-tile 0..3
    int m0 = nt * 128;                // d
    int n0 = blockIdx.y * 128;        // t global
    int b  = blockIdx.y >> 4;
    int tt = blockIdx.y & 15;
    int wave = tid >> 6, lane = tid & 63;
    int wm = wave >> 1, wn = wave & 1;
    int q = lane >> 4, l16 = lane & 15;
    int r = tid >> 1, c0 = (tid & 1) << 4;

    const ushort_t* gah = Mbf + (size_t)(m0 + r) * DIM + c0;
    const ushort_t* gbh = Ehi + (size_t)(n0 + r) * DIM + c0;

    const f32x4 fz = {0.f, 0.f, 0.f, 0.f};
    f32x4 acc[4][4];
#pragma unroll
    for (int i = 0; i < 4; ++i)
#pragma unroll
        for (int j = 0; j < 4; ++j) acc[i][j] = fz;

    for (int k0 = 0; k0 < DIM; k0 += 32) {
        u16x8 a0 = *(const u16x8*)(gah + k0);
        u16x8 a1 = *(const u16x8*)(gah + k0 + 8);
        u16x8 b0 = *(const u16x8*)(gbh + k0);
        u16x8 b1 = *(const u16x8*)(gbh + k0 + 8);
        __syncthreads();
        *(u16x8*)&Ah[r][c0] = a0; *(u16x8*)&Ah[r][c0 + 8] = a1;
        *(u16x8*)&Bh[r][c0] = b0; *(u16x8*)&Bh[r][c0 + 8] = b1;
        __syncthreads();
        bf16x8 fa[4], fb[4];
#pragma unroll
        for (int t = 0; t < 4; ++t) {
            int ar = wm * 64 + t * 16 + l16;
            int br = wn * 64 + t * 16 + l16;
            fa[t] = *(const bf16x8*)&Ah[ar][q * 8];
            fb[t] = *(const bf16x8*)&Bh[br][q * 8];
        }
#pragma unroll
        for (int i = 0; i < 4; ++i)
#pragma unroll
            for (int j = 0; j < 4; ++j)
                acc[i][j] = __builtin_amdgcn_mfma_f32_16x16x32_bf16(fa[i], fb[j], acc[i][j], 0, 0, 0);
    }
#pragma unroll
    for (int i = 0; i < 4; ++i)
#pragma unroll
        for (int j = 0; j < 4; ++j) {
            int col = wn * 64 + j * 16 + l16;   // t-local
            f32x4 c = acc[i][j];
#pragma unroll
            for (int rr = 0; rr < 4; ++rr) {
                int row = wm * 64 + i * 16 + q * 4 + rr;   // d-local
                Ct[row][col] = f2bf(c[rr]);
            }
        }
    __syncthreads();
    int cc = tid >> 7, tr = tid & 127;
    size_t tbase = ((size_t)(b * 4 + nt) * 32 + tt * 2 + cc) * 8192 + (size_t)tr * 64;
#pragma unroll
    for (int p = 0; p < 8; ++p)
        *(u16x8*)(VLT + tbase + p * 8) = *(const u16x8*)&Ct[tr][cc * 64 + p * 8];
}

// ---------------------------------------------------------------------------
// K3: scores S[b][i][j] = sum_g H[b,i,g]*E[b,j,g]  — 3-pass, 32x32x16 MFMA
// ---------------------------------------------------------------------------
__global__ __launch_bounds__(256) void k_scores(const ushort_t* __restrict__ Hhi, const ushort_t* __restrict__ Hlo,
                                                const ushort_t* __restrict__ Ehi, const ushort_t* __restrict__ Elo,
                                                float* __restrict__ S) {
    __shared__ ushort_t Ah[128][40], Al[128][40], Bh[128][40], Bl[128][40];
    int tid = threadIdx.x;
    int b = blockIdx.z;
    int m0 = blockIdx.x * 128;
    int n0 = blockIdx.y * 128;
    int wave = tid >> 6, lane = tid & 63;
    int wm = wave >> 1, wn = wave & 1;
    int l32 = lane & 31, kh = lane >> 5;
    int r = tid >> 1, c0 = (tid & 1) << 4;

    const ushort_t* gah = Hhi + ((size_t)b * TSEQ + m0 + r) * DIM + c0;
    const ushort_t* gal = Hlo + ((size_t)b * TSEQ + m0 + r) * DIM + c0;
    const ushort_t* gbh = Ehi + ((size_t)b * TSEQ + n0 + r) * DIM + c0;
    const ushort_t* gbl = Elo + ((size_t)b * TSEQ + n0 + r) * DIM + c0;

    f32x16 acc[2][2];
#pragma unroll
    for (int i = 0; i < 2; ++i)
#pragma unroll
        for (int j = 0; j < 2; ++j)
#pragma unroll
            for (int t = 0; t < 16; ++t) acc[i][j][t] = 0.f;

    for (int k0 = 0; k0 < DIM; k0 += 32) {
        u16x8 a0 = *(const u16x8*)(gah + k0);
        u16x8 a1 = *(const u16x8*)(gah + k0 + 8);
        u16x8 a2 = *(const u16x8*)(gal + k0);
        u16x8 a3 = *(const u16x8*)(gal + k0 + 8);
        u16x8 b0 = *(const u16x8*)(gbh + k0);
        u16x8 b1 = *(const u16x8*)(gbh + k0 + 8);
        u16x8 b2 = *(const u16x8*)(gbl + k0);
        u16x8 b3 = *(const u16x8*)(gbl + k0 + 8);
        __syncthreads();
        *(u16x8*)&Ah[r][c0] = a0; *(u16x8*)&Ah[r][c0 + 8] = a1;
        *(u16x8*)&Al[r][c0] = a2; *(u16x8*)&Al[r][c0 + 8] = a3;
        *(u16x8*)&Bh[r][c0] = b0; *(u16x8*)&Bh[r][c0 + 8] = b1;
        *(u16x8*)&Bl[r][c0] = b2; *(u16x8*)&Bl[r][c0 + 8] = b3;
        __syncthreads();
        bf16x8 fah[2][2], fal[2][2], fbh[2][2], fbl[2][2];
#pragma unroll
        for (int mt = 0; mt < 2; ++mt)
#pragma unroll
            for (int kc = 0; kc < 2; ++kc) {
                int ar = wm * 64 + mt * 32 + l32;
                int ka = kc * 16 + kh * 8;
                fah[mt][kc] = *(const bf16x8*)&Ah[ar][ka];
                fal[mt][kc] = *(const bf16x8*)&Al[ar][ka];
                int br = wn * 64 + mt * 32 + l32;
                fbh[mt][kc] = *(const bf16x8*)&Bh[br][ka];
                fbl[mt][kc] = *(const bf16x8*)&Bl[br][ka];
            }
#pragma unroll
        for (int mt = 0; mt < 2; ++mt)
#pragma unroll
            for (int nt = 0; nt < 2; ++nt) {
                f32x16 c = acc[mt][nt];
#pragma unroll
                for (int kc = 0; kc < 2; ++kc) {
                    c = __builtin_amdgcn_mfma_f32_32x32x16_bf16(fal[mt][kc], fbh[nt][kc], c, 0, 0, 0);
                    c = __builtin_amdgcn_mfma_f32_32x32x16_bf16(fah[mt][kc], fbl[nt][kc], c, 0, 0, 0);
                    c = __builtin_amdgcn_mfma_f32_32x32x16_bf16(fah[mt][kc], fbh[nt][kc], c, 0, 0, 0);
                }
                acc[mt][nt] = c;
            }
    }
    float* Sout = S + (size_t)b * TSEQ * TSEQ;
#pragma unroll
    for (int mt = 0; mt < 2; ++mt)
#pragma unroll
        for (int nt = 0; nt < 2; ++nt) {
            int col = n0 + wn * 64 + nt * 32 + l32;
            f32x16 c = acc[mt][nt];
#pragma unroll
            for (int rr = 0; rr < 16; ++rr) {
                int row = m0 + wm * 64 + mt * 32 + (rr & 3) + 8 * (rr >> 2) + 4 * kh;
                Sout[(size_t)row * TSEQ + col] = c[rr];
            }
        }
}

// ---------------------------------------------------------------------------
// K4: softexp: row max + sum; P = bf16(exp(S-m)/l) written TILED
// ---------------------------------------------------------------------------
__global__ __launch_bounds__(256) void k_softexp(const float* __restrict__ S,
                                                 ushort_t* __restrict__ P) {
    int row = blockIdx.x;                 // 0..16383
    int tid = threadIdx.x;
    const float* r = S + (size_t)row * TSEQ;
    float4 v0 = *(const float4*)(r + tid * 8);
    float4 v1 = *(const float4*)(r + tid * 8 + 4);
    float vv[8] = {v0.x, v0.y, v0.z, v0.w, v1.x, v1.y, v1.z, v1.w};
    float mx = vv[0];
#pragma unroll
    for (int i = 1; i < 8; ++i) mx = fmaxf(mx, vv[i]);
#pragma unroll
    for (int off = 32; off > 0; off >>= 1) mx = fmaxf(mx, __shfl_xor(mx, off));
    __shared__ float sm[4];
    __shared__ float sl[4];
    if ((tid & 63) == 0) sm[tid >> 6] = mx;
    __syncthreads();
    mx = fmaxf(fmaxf(sm[0], sm[1]), fmaxf(sm[2], sm[3]));
    float e[8];
    float s = 0.f;
#pragma unroll
    for (int i = 0; i < 8; ++i) {
        e[i] = __expf(vv[i] - mx);
        s += e[i];
    }
#pragma unroll
    for (int off = 32; off > 0; off >>= 1) s += __shfl_xor(s, off);
    if ((tid & 63) == 0) sl[tid >> 6] = s;
    __syncthreads();
    float linv = 1.f / (sl[0] + sl[1] + sl[2] + sl[3]);
    u16x8 p;
#pragma unroll
    for (int i = 0; i < 8; ++i) p[i] = f2bf(e[i] * linv);
    int b = row >> 11, i = row & 2047;
    int it = i >> 7, rr = i & 127;
    size_t dst = ((size_t)(b * 16 + it) * 32 + (tid >> 3)) * 8192 + (size_t)rr * 64 + (tid & 7) * 8;
    *(u16x8*)(P + dst) = p;
}

// ---------------------------------------------------------------------------
// K5: PV: Y = P . V (tiled operands, 32x32x16, BK=64); + bias, relu,
//     reduce over i -> accg
// ---------------------------------------------------------------------------
__global__ __launch_bounds__(256) void k_pv(const ushort_t* __restrict__ P,
                                            const ushort_t* __restrict__ VLT,
                                            const float* __restrict__ lin_b,
                                            float* __restrict__ accg) {
    __shared__ ushort_t As[128][72], Bs[128][72];
    __shared__ float bias_s[128];
    int tid = threadIdx.x;
    int b  = blockIdx.z;
    int it = blockIdx.x;                 // i-tile 0..15
    int nt = blockIdx.y;                 // d-tile 0..3
    int n0 = nt * 128;
    if (tid < 128) bias_s[tid] = lin_b[n0 + tid];
    int wave = tid >> 6, lane = tid & 63;
    int wm = wave >> 1, wn = wave & 1;
    int l32 = lane & 31, kh = lane >> 5;
    int r = tid >> 1, c0 = (tid & 1) << 5;   // 0 or 32

    const ushort_t* pa = P   + ((size_t)(b * 16 + it) * 32) * 8192 + (size_t)r * 64 + c0;
    const ushort_t* pb = VLT + ((size_t)(b * 4  + nt) * 32) * 8192 + (size_t)r * 64 + c0;

    f32x16 acc[2][2];
#pragma unroll
    for (int i = 0; i < 2; ++i)
#pragma unroll
        for (int j = 0; j < 2; ++j)
#pragma unroll
            for (int t = 0; t < 16; ++t) acc[i][j][t] = 0.f;

    for (int kc = 0; kc < 32; ++kc) {
        const ushort_t* sa = pa + (size_t)kc * 8192;
        const ushort_t* sb = pb + (size_t)kc * 8192;
        u16x8 a0 = *(const u16x8*)(sa);
        u16x8 a1 = *(const u16x8*)(sa + 8);
        u16x8 a2 = *(const u16x8*)(sa + 16);
        u16x8 a3 = *(const u16x8*)(sa + 24);
        u16x8 vb0 = *(const u16x8*)(sb);
        u16x8 vb1 = *(const u16x8*)(sb + 8);
        u16x8 vb2 = *(const u16x8*)(sb + 16);
        u16x8 vb3 = *(const u16x8*)(sb + 24);
        __syncthreads();
        *(u16x8*)&As[r][c0]      = a0;  *(u16x8*)&As[r][c0 + 8]  = a1;
        *(u16x8*)&As[r][c0 + 16] = a2;  *(u16x8*)&As[r][c0 + 24] = a3;
        *(u16x8*)&Bs[r][c0]      = vb0; *(u16x8*)&Bs[r][c0 + 8]  = vb1;
        *(u16x8*)&Bs[r][c0 + 16] = vb2; *(u16x8*)&Bs[r][c0 + 24] = vb3;
        __syncthreads();
#pragma unroll
        for (int kk = 0; kk < 4; ++kk) {
            int ka = kk * 16 + kh * 8;
            bf16x8 fa[2], fb[2];
#pragma unroll
            for (int mt = 0; mt < 2; ++mt) {
                fa[mt] = *(const bf16x8*)&As[wm * 64 + mt * 32 + l32][ka];
                fb[mt] = *(const bf16x8*)&Bs[wn * 64 + mt * 32 + l32][ka];
            }
#pragma unroll
            for (int mt = 0; mt < 2; ++mt)
#pragma unroll
                for (int dt = 0; dt < 2; ++dt)
                    acc[mt][dt] = __builtin_amdgcn_mfma_f32_32x32x16_bf16(fa[mt], fb[dt], acc[mt][dt], 0, 0, 0);
        }
    }
    float dsum[2] = {0.f, 0.f};
#pragma unroll
    for (int mt = 0; mt < 2; ++mt)
#pragma unroll
        for (int dt = 0; dt < 2; ++dt) {
            f32x16 c = acc[mt][dt];
            float bias = bias_s[wn * 64 + dt * 32 + l32];
#pragma unroll
            for (int rr = 0; rr < 16; ++rr)
                dsum[dt] += fmaxf(c[rr] + bias, 0.f);
        }
#pragma unroll
    for (int dt = 0; dt < 2; ++dt) {
        float v = dsum[dt];
        v += __shfl_xor(v, 32);
        if (kh == 0) atomicAdd(&accg[b * DIM + n0 + wn * 64 + dt * 32 + l32], v);
    }
}

// ---------------------------------------------------------------------------
// K6: out[b] = sigmoid((accg[b]/T) . clf_w + clf_b)
// ---------------------------------------------------------------------------
__global__ void k_final(const float* __restrict__ accg,
                        const float* __restrict__ clf_w,
                        const float* __restrict__ clf_b,
                        float* __restrict__ out) {
    int tid  = threadIdx.x;
    int b    = tid >> 6;
    int lane = tid & 63;
    float s = 0.f;
    for (int d = lane; d < DIM; d += 64) s = fmaf(accg[b * DIM + d], clf_w[d], s);
#pragma unroll
    for (int off = 32; off > 0; off >>= 1) s += __shfl_xor(s, off);
    if (lane == 0) {
        float z = s * (1.0f / TSEQ) + clf_b[0];
        out[b] = 1.f / (1.f + __expf(-z));
    }
}

// ---------------------------------------------------------------------------
extern "C" void kernel_launch(void* const* d_in, const int* in_sizes, int n_in,
                              void* d_out, int out_size, void* d_ws, size_t ws_size,
                              hipStream_t stream) {
    const int*   x     = (const int*)d_in[0];
    const float* embed = (const float*)d_in[1];
    const float* Wq    = (const float*)d_in[2];
    const float* Wk    = (const float*)d_in[3];
    const float* Wv    = (const float*)d_in[4];
    const float* lin_w = (const float*)d_in[5];
    const float* lin_b = (const float*)d_in[6];
    const float* clf_w = (const float*)d_in[7];
    const float* clf_b = (const float*)d_in[8];
    float* out = (float*)d_out;

    char* wsb = (char*)d_ws;
    float* S = (float*)wsb;                                  // 134 MB
    char* p = wsb + (size_t)NB * TSEQ * TSEQ * 4;
    ushort_t* Ehi  = (ushort_t*)p;                           // 67 MB E/H block
    ushort_t* Elo  = Ehi  + (size_t)BTOT * DIM;
    ushort_t* Hhi  = Elo  + (size_t)BTOT * DIM;
    ushort_t* Hlo  = Hhi  + (size_t)BTOT * DIM;
    ushort_t* Pt   = Ehi;                                    // aliases E/H (dead after scores)
    ushort_t* VLT  = Hlo  + (size_t)BTOT * DIM;              // 16.8 MB tiled
    ushort_t* Gthi = VLT  + (size_t)DIM * BTOT;
    ushort_t* Gtlo = Gthi + (size_t)DIM * DIM;
    ushort_t* Mbf  = Gtlo + (size_t)DIM * DIM;
    float* accg = (float*)(Mbf + (size_t)DIM * DIM);

    hipMemsetAsync(accg, 0, NB * DIM * sizeof(float), stream);
    k_split_embed<<<BTOT * 64 / 256, 256, 0, stream>>>(x, embed, Ehi, Elo);
    k_wgemm<<<dim3(16, 16, 2), 256, 0, stream>>>(Wq, Wk, lin_w, Wv, Gthi, Gtlo, Mbf);
    k_proj_h<<<dim3(128, 4), 256, 0, stream>>>(Ehi, Elo, Gthi, Gtlo, Hhi, Hlo);
    k_proj_vlt<<<dim3(4, 128), 256, 0, stream>>>(Mbf, Ehi, VLT);
    k_scores<<<dim3(16, 16, 8), 256, 0, stream>>>(Hhi, Hlo, Ehi, Elo, S);
    k_softexp<<<BTOT, 256, 0, stream>>>(S, Pt);
    k_pv<<<dim3(16, 4, 8), 256, 0, stream>>>(Pt, VLT, lin_b, accg);
    k_final<<<1, 512, 0, stream>>>(accg, clf_w, clf_b, out);
}

// Round 9
// 363.469 us; speedup vs baseline: 1.0892x; 1.0892x over previous
//
#include <hip/hip_runtime.h>
#include <math.h>

#define TSEQ 2048
#define DIM  512
#define NB   8
#define BTOT 16384
#define SCALE 0.04419417382415922f

typedef __attribute__((ext_vector_type(8))) short bf16x8;
typedef __attribute__((ext_vector_type(4))) float f32x4;
typedef __attribute__((ext_vector_type(16))) float f32x16;
typedef __attribute__((ext_vector_type(8))) unsigned short u16x8;
typedef __attribute__((ext_vector_type(4))) unsigned short u16x4;
typedef unsigned short ushort_t;

__device__ __forceinline__ unsigned short f2bf(float f) {
    unsigned u = __builtin_bit_cast(unsigned, f);
    u += 0x7FFFu + ((u >> 16) & 1u);
    return (unsigned short)(u >> 16);
}
__device__ __forceinline__ float bf2f(unsigned short h) {
    unsigned u = ((unsigned)h) << 16;
    return __builtin_bit_cast(float, u);
}

// ---------------------------------------------------------------------------
// P0: gather embedding rows, split to hi/lo bf16
// ---------------------------------------------------------------------------
__global__ __launch_bounds__(256) void k_split_embed(const int* __restrict__ x,
                                                     const float* __restrict__ embed,
                                                     ushort_t* __restrict__ Ehi,
                                                     ushort_t* __restrict__ Elo) {
    int idx = blockIdx.x * 256 + threadIdx.x;
    int row = idx >> 6;
    int c   = (idx & 63) << 3;
    int tok = x[row];
    const float* src = embed + (size_t)tok * DIM + c;
    float4 v0 = *(const float4*)src;
    float4 v1 = *(const float4*)(src + 4);
    float vv[8] = {v0.x, v0.y, v0.z, v0.w, v1.x, v1.y, v1.z, v1.w};
    u16x8 h, l;
#pragma unroll
    for (int i = 0; i < 8; ++i) {
        unsigned short hh = f2bf(vv[i]);
        h[i] = hh;
        l[i] = f2bf(vv[i] - bf2f(hh));
    }
    *(u16x8*)(Ehi + (size_t)row * DIM + c) = h;
    *(u16x8*)(Elo + (size_t)row * DIM + c) = l;
}

// ---------------------------------------------------------------------------
// P1: fused small fp32 SGEMMs (512x512x512 each), LDS-tiled 32x32, grid (16,16,2)
//   seg 0: Gt[g][f] = SCALE * sum_d Wk[d][g] * Wq[d][f]  -> hi/lo bf16 split
//   seg 1: M [d][f] =         sum_g lin_w[d][g] * Wv[g][f] -> single bf16
// ---------------------------------------------------------------------------
__global__ __launch_bounds__(256) void k_wgemm(const float* __restrict__ Wq,
                                               const float* __restrict__ Wk,
                                               const float* __restrict__ lin_w,
                                               const float* __restrict__ Wv,
                                               ushort_t* __restrict__ Gthi,
                                               ushort_t* __restrict__ Gtlo,
                                               ushort_t* __restrict__ Mbf) {
    __shared__ float As[32][33];
    __shared__ float Bs[32][33];
    int tid = threadIdx.x;
    int seg = blockIdx.z;
    int m0 = blockIdx.x * 32;
    int n0 = blockIdx.y * 32;
    int dr = tid >> 3;
    int c4 = (tid & 7) * 4;
    int tx = tid & 15, ty = tid >> 4;

    const float* Bsrc = seg ? Wv : Wq;
    float acc[2][2] = {{0.f, 0.f}, {0.f, 0.f}};

    for (int k0 = 0; k0 < DIM; k0 += 32) {
        float4 a4, b4;
        if (seg == 0) {
            a4 = *(const float4*)(Wk + (size_t)(k0 + dr) * DIM + m0 + c4);
        } else {
            a4 = *(const float4*)(lin_w + (size_t)(m0 + dr) * DIM + k0 + c4);
        }
        b4 = *(const float4*)(Bsrc + (size_t)(k0 + dr) * DIM + n0 + c4);
        __syncthreads();
        if (seg == 0) {
            *(float4*)&As[dr][c4] = a4;
        } else {
            As[c4 + 0][dr] = a4.x; As[c4 + 1][dr] = a4.y;
            As[c4 + 2][dr] = a4.z; As[c4 + 3][dr] = a4.w;
        }
        *(float4*)&Bs[dr][c4] = b4;
        __syncthreads();
#pragma unroll
        for (int k = 0; k < 32; ++k) {
            float a0 = As[k][ty * 2], a1 = As[k][ty * 2 + 1];
            float b0 = Bs[k][tx * 2], b1 = Bs[k][tx * 2 + 1];
            acc[0][0] = fmaf(a0, b0, acc[0][0]);
            acc[0][1] = fmaf(a0, b1, acc[0][1]);
            acc[1][0] = fmaf(a1, b0, acc[1][0]);
            acc[1][1] = fmaf(a1, b1, acc[1][1]);
        }
    }
#pragma unroll
    for (int i = 0; i < 2; ++i)
#pragma unroll
        for (int j = 0; j < 2; ++j) {
            int row = m0 + ty * 2 + i;
            int col = n0 + tx * 2 + j;
            if (seg == 0) {
                float v = acc[i][j] * SCALE;
                unsigned short hh = f2bf(v);
                Gthi[(size_t)row * DIM + col] = hh;
                Gtlo[(size_t)row * DIM + col] = f2bf(v - bf2f(hh));
            } else {
                Mbf[(size_t)row * DIM + col] = f2bf(acc[i][j]);
            }
        }
}

// ---------------------------------------------------------------------------
// K1: H = E . Gt^T  (3-pass split-bf16, 16x16x32), outputs hi/lo bf16
// ---------------------------------------------------------------------------
__global__ __launch_bounds__(256) void k_proj_h(const ushort_t* __restrict__ Ehi, const ushort_t* __restrict__ Elo,
                                                const ushort_t* __restrict__ Gthi, const ushort_t* __restrict__ Gtlo,
                                                ushort_t* __restrict__ Hhi, ushort_t* __restrict__ Hlo) {
    __shared__ ushort_t Ah[128][40], Al[128][40], Bh[128][40], Bl[128][40];
    int tid = threadIdx.x;
    int m0 = blockIdx.x * 128;
    int n0 = blockIdx.y * 128;

    int wave = tid >> 6, lane = tid & 63;
    int wm = wave >> 1, wn = wave & 1;
    int q = lane >> 4, l16 = lane & 15;
    int r = tid >> 1, c0 = (tid & 1) << 4;

    const ushort_t* gah = Ehi + (size_t)(m0 + r) * DIM + c0;
    const ushort_t* gal = Elo + (size_t)(m0 + r) * DIM + c0;
    const ushort_t* gbh = Gthi + (size_t)(n0 + r) * DIM + c0;
    const ushort_t* gbl = Gtlo + (size_t)(n0 + r) * DIM + c0;

    const f32x4 fz = {0.f, 0.f, 0.f, 0.f};
    f32x4 acc[4][4];
#pragma unroll
    for (int i = 0; i < 4; ++i)
#pragma unroll
        for (int j = 0; j < 4; ++j) acc[i][j] = fz;

    for (int k0 = 0; k0 < DIM; k0 += 32) {
        u16x8 a0 = *(const u16x8*)(gah + k0);
        u16x8 a1 = *(const u16x8*)(gah + k0 + 8);
        u16x8 a2 = *(const u16x8*)(gal + k0);
        u16x8 a3 = *(const u16x8*)(gal + k0 + 8);
        u16x8 b0 = *(const u16x8*)(gbh + k0);
        u16x8 b1 = *(const u16x8*)(gbh + k0 + 8);
        u16x8 b2 = *(const u16x8*)(gbl + k0);
        u16x8 b3 = *(const u16x8*)(gbl + k0 + 8);
        __syncthreads();
        *(u16x8*)&Ah[r][c0] = a0; *(u16x8*)&Ah[r][c0 + 8] = a1;
        *(u16x8*)&Al[r][c0] = a2; *(u16x8*)&Al[r][c0 + 8] = a3;
        *(u16x8*)&Bh[r][c0] = b0; *(u16x8*)&Bh[r][c0 + 8] = b1;
        *(u16x8*)&Bl[r][c0] = b2; *(u16x8*)&Bl[r][c0 + 8] = b3;
        __syncthreads();
        bf16x8 fah[4], fal[4], fbh[4], fbl[4];
#pragma unroll
        for (int t = 0; t < 4; ++t) {
            int ar = wm * 64 + t * 16 + l16;
            int br = wn * 64 + t * 16 + l16;
            fah[t] = *(const bf16x8*)&Ah[ar][q * 8];
            fal[t] = *(const bf16x8*)&Al[ar][q * 8];
            fbh[t] = *(const bf16x8*)&Bh[br][q * 8];
            fbl[t] = *(const bf16x8*)&Bl[br][q * 8];
        }
#pragma unroll
        for (int i = 0; i < 4; ++i)
#pragma unroll
            for (int j = 0; j < 4; ++j) {
                f32x4 c = acc[i][j];
                c = __builtin_amdgcn_mfma_f32_16x16x32_bf16(fal[i], fbh[j], c, 0, 0, 0);
                c = __builtin_amdgcn_mfma_f32_16x16x32_bf16(fah[i], fbl[j], c, 0, 0, 0);
                c = __builtin_amdgcn_mfma_f32_16x16x32_bf16(fah[i], fbh[j], c, 0, 0, 0);
                acc[i][j] = c;
            }
    }
#pragma unroll
    for (int i = 0; i < 4; ++i)
#pragma unroll
        for (int j = 0; j < 4; ++j) {
            int col = n0 + wn * 64 + j * 16 + l16;
            f32x4 c = acc[i][j];
#pragma unroll
            for (int rr = 0; rr < 4; ++rr) {
                int row = m0 + wm * 64 + i * 16 + q * 4 + rr;
                float v = c[rr];
                unsigned short hh = f2bf(v);
                Hhi[(size_t)row * DIM + col] = hh;
                Hlo[(size_t)row * DIM + col] = f2bf(v - bf2f(hh));
            }
        }
}

// ---------------------------------------------------------------------------
// K2: VLT[d][t] = sum_f Mbf[d][f] * Ehi[t][f]  (single-pass bf16), d-major
//     Epilogue: LDS transpose tile -> coalesced u16x4 stores.
// ---------------------------------------------------------------------------
__global__ __launch_bounds__(256) void k_proj_vlt(const ushort_t* __restrict__ Mbf,
                                                  const ushort_t* __restrict__ Ehi,
                                                  ushort_t* __restrict__ VLT) {
    __shared__ ushort_t Ah[128][40], Bh[128][40];
    __shared__ ushort_t Ct[128][132];
    int tid = threadIdx.x;
    int m0 = blockIdx.x * 128;   // d
    int n0 = blockIdx.y * 128;   // t
    int wave = tid >> 6, lane = tid & 63;
    int wm = wave >> 1, wn = wave & 1;
    int q = lane >> 4, l16 = lane & 15;
    int r = tid >> 1, c0 = (tid & 1) << 4;

    const ushort_t* gah = Mbf + (size_t)(m0 + r) * DIM + c0;
    const ushort_t* gbh = Ehi + (size_t)(n0 + r) * DIM + c0;

    const f32x4 fz = {0.f, 0.f, 0.f, 0.f};
    f32x4 acc[4][4];
#pragma unroll
    for (int i = 0; i < 4; ++i)
#pragma unroll
        for (int j = 0; j < 4; ++j) acc[i][j] = fz;

    for (int k0 = 0; k0 < DIM; k0 += 32) {
        u16x8 a0 = *(const u16x8*)(gah + k0);
        u16x8 a1 = *(const u16x8*)(gah + k0 + 8);
        u16x8 b0 = *(const u16x8*)(gbh + k0);
        u16x8 b1 = *(const u16x8*)(gbh + k0 + 8);
        __syncthreads();
        *(u16x8*)&Ah[r][c0] = a0; *(u16x8*)&Ah[r][c0 + 8] = a1;
        *(u16x8*)&Bh[r][c0] = b0; *(u16x8*)&Bh[r][c0 + 8] = b1;
        __syncthreads();
        bf16x8 fa[4], fb[4];
#pragma unroll
        for (int t = 0; t < 4; ++t) {
            int ar = wm * 64 + t * 16 + l16;
            int br = wn * 64 + t * 16 + l16;
            fa[t] = *(const bf16x8*)&Ah[ar][q * 8];
            fb[t] = *(const bf16x8*)&Bh[br][q * 8];
        }
#pragma unroll
        for (int i = 0; i < 4; ++i)
#pragma unroll
            for (int j = 0; j < 4; ++j)
                acc[i][j] = __builtin_amdgcn_mfma_f32_16x16x32_bf16(fa[i], fb[j], acc[i][j], 0, 0, 0);
    }
    // stage C tile (d-local x t-local) in LDS
#pragma unroll
    for (int i = 0; i < 4; ++i)
#pragma unroll
        for (int j = 0; j < 4; ++j) {
            int col = wn * 64 + j * 16 + l16;
            f32x4 c = acc[i][j];
#pragma unroll
            for (int rr = 0; rr < 4; ++rr) {
                int row = wm * 64 + i * 16 + q * 4 + rr;
                Ct[row][col] = f2bf(c[rr]);
            }
        }
    __syncthreads();
    // coalesced store: 32 consecutive lanes cover 128 contiguous shorts of a row
    int sc  = (tid & 31) * 4;
    int sr0 = tid >> 5;
#pragma unroll
    for (int p = 0; p < 16; ++p) {
        int row = p * 8 + sr0;
        *(u16x4*)(VLT + (size_t)(m0 + row) * BTOT + n0 + sc) = *(const u16x4*)&Ct[row][sc];
    }
}

// ---------------------------------------------------------------------------
// K3: scores S[b][i][j] = sum_g H[b,i,g]*E[b,j,g]  — 3-pass, 32x32x16 MFMA
// ---------------------------------------------------------------------------
__global__ __launch_bounds__(256) void k_scores(const ushort_t* __restrict__ Hhi, const ushort_t* __restrict__ Hlo,
                                                const ushort_t* __restrict__ Ehi, const ushort_t* __restrict__ Elo,
                                                float* __restrict__ S) {
    __shared__ ushort_t Ah[128][40], Al[128][40], Bh[128][40], Bl[128][40];
    int tid = threadIdx.x;
    int b = blockIdx.z;
    int m0 = blockIdx.x * 128;
    int n0 = blockIdx.y * 128;
    int wave = tid >> 6, lane = tid & 63;
    int wm = wave >> 1, wn = wave & 1;
    int l32 = lane & 31, kh = lane >> 5;
    int r = tid >> 1, c0 = (tid & 1) << 4;

    const ushort_t* gah = Hhi + ((size_t)b * TSEQ + m0 + r) * DIM + c0;
    const ushort_t* gal = Hlo + ((size_t)b * TSEQ + m0 + r) * DIM + c0;
    const ushort_t* gbh = Ehi + ((size_t)b * TSEQ + n0 + r) * DIM + c0;
    const ushort_t* gbl = Elo + ((size_t)b * TSEQ + n0 + r) * DIM + c0;

    f32x16 acc[2][2];
#pragma unroll
    for (int i = 0; i < 2; ++i)
#pragma unroll
        for (int j = 0; j < 2; ++j)
#pragma unroll
            for (int t = 0; t < 16; ++t) acc[i][j][t] = 0.f;

    for (int k0 = 0; k0 < DIM; k0 += 32) {
        u16x8 a0 = *(const u16x8*)(gah + k0);
        u16x8 a1 = *(const u16x8*)(gah + k0 + 8);
        u16x8 a2 = *(const u16x8*)(gal + k0);
        u16x8 a3 = *(const u16x8*)(gal + k0 + 8);
        u16x8 b0 = *(const u16x8*)(gbh + k0);
        u16x8 b1 = *(const u16x8*)(gbh + k0 + 8);
        u16x8 b2 = *(const u16x8*)(gbl + k0);
        u16x8 b3 = *(const u16x8*)(gbl + k0 + 8);
        __syncthreads();
        *(u16x8*)&Ah[r][c0] = a0; *(u16x8*)&Ah[r][c0 + 8] = a1;
        *(u16x8*)&Al[r][c0] = a2; *(u16x8*)&Al[r][c0 + 8] = a3;
        *(u16x8*)&Bh[r][c0] = b0; *(u16x8*)&Bh[r][c0 + 8] = b1;
        *(u16x8*)&Bl[r][c0] = b2; *(u16x8*)&Bl[r][c0 + 8] = b3;
        __syncthreads();
        bf16x8 fah[2][2], fal[2][2], fbh[2][2], fbl[2][2];
#pragma unroll
        for (int mt = 0; mt < 2; ++mt)
#pragma unroll
            for (int kc = 0; kc < 2; ++kc) {
                int ar = wm * 64 + mt * 32 + l32;
                int ka = kc * 16 + kh * 8;
                fah[mt][kc] = *(const bf16x8*)&Ah[ar][ka];
                fal[mt][kc] = *(const bf16x8*)&Al[ar][ka];
                int br = wn * 64 + mt * 32 + l32;
                fbh[mt][kc] = *(const bf16x8*)&Bh[br][ka];
                fbl[mt][kc] = *(const bf16x8*)&Bl[br][ka];
            }
#pragma unroll
        for (int mt = 0; mt < 2; ++mt)
#pragma unroll
            for (int nt = 0; nt < 2; ++nt) {
                f32x16 c = acc[mt][nt];
#pragma unroll
                for (int kc = 0; kc < 2; ++kc) {
                    c = __builtin_amdgcn_mfma_f32_32x32x16_bf16(fal[mt][kc], fbh[nt][kc], c, 0, 0, 0);
                    c = __builtin_amdgcn_mfma_f32_32x32x16_bf16(fah[mt][kc], fbl[nt][kc], c, 0, 0, 0);
                    c = __builtin_amdgcn_mfma_f32_32x32x16_bf16(fah[mt][kc], fbh[nt][kc], c, 0, 0, 0);
                }
                acc[mt][nt] = c;
            }
    }
    float* Sout = S + (size_t)b * TSEQ * TSEQ;
#pragma unroll
    for (int mt = 0; mt < 2; ++mt)
#pragma unroll
        for (int nt = 0; nt < 2; ++nt) {
            int col = n0 + wn * 64 + nt * 32 + l32;
            f32x16 c = acc[mt][nt];
#pragma unroll
            for (int rr = 0; rr < 16; ++rr) {
                int row = m0 + wm * 64 + mt * 32 + (rr & 3) + 8 * (rr >> 2) + 4 * kh;
                Sout[(size_t)row * TSEQ + col] = c[rr];
            }
        }
}

// ---------------------------------------------------------------------------
// K4: softexp: row max, P = bf16(exp(S-m)) aliased into S, linv = 1/sum
// ---------------------------------------------------------------------------
__global__ __launch_bounds__(256) void k_softexp(float* __restrict__ S,
                                                 float* __restrict__ linv) {
    int row = blockIdx.x;
    int tid = threadIdx.x;
    float* r = S + (size_t)row * TSEQ;
    ushort_t* Prow = (ushort_t*)S + (size_t)row * 4096;
    float4 v0 = *(const float4*)(r + tid * 8);
    float4 v1 = *(const float4*)(r + tid * 8 + 4);
    float vv[8] = {v0.x, v0.y, v0.z, v0.w, v1.x, v1.y, v1.z, v1.w};
    float mx = vv[0];
#pragma unroll
    for (int i = 1; i < 8; ++i) mx = fmaxf(mx, vv[i]);
#pragma unroll
    for (int off = 32; off > 0; off >>= 1) mx = fmaxf(mx, __shfl_xor(mx, off));
    __shared__ float sm[4];
    __shared__ float sl[4];
    if ((tid & 63) == 0) sm[tid >> 6] = mx;
    __syncthreads();
    mx = fmaxf(fmaxf(sm[0], sm[1]), fmaxf(sm[2], sm[3]));
    float e[8];
    float s = 0.f;
    u16x8 p;
#pragma unroll
    for (int i = 0; i < 8; ++i) {
        e[i] = __expf(vv[i] - mx);
        s += e[i];
        p[i] = f2bf(e[i]);
    }
    *(u16x8*)(Prow + tid * 8) = p;
#pragma unroll
    for (int off = 32; off > 0; off >>= 1) s += __shfl_xor(s, off);
    if ((tid & 63) == 0) sl[tid >> 6] = s;
    __syncthreads();
    if (tid == 0) linv[row] = 1.f / (sl[0] + sl[1] + sl[2] + sl[3]);
}

// ---------------------------------------------------------------------------
// K5: PV: Y = P . VLT^T  (32x32x16, BK=64); *linv + bias, relu, reduce -> accg
// ---------------------------------------------------------------------------
__global__ __launch_bounds__(256) void k_pv(const float* __restrict__ Sbase,
                                            const ushort_t* __restrict__ VLT,
                                            const float* __restrict__ linv,
                                            const float* __restrict__ lin_b,
                                            float* __restrict__ accg) {
    __shared__ ushort_t As[128][72], Bs[128][72];
    __shared__ float linv_s[128], bias_s[128];
    int tid = threadIdx.x;
    int b  = blockIdx.z;
    int m0 = blockIdx.x * 128;   // i
    int n0 = blockIdx.y * 128;   // d
    if (tid < 128) {
        linv_s[tid] = linv[b * TSEQ + m0 + tid];
        bias_s[tid] = lin_b[n0 + tid];
    }
    int wave = tid >> 6, lane = tid & 63;
    int wm = wave >> 1, wn = wave & 1;
    int l32 = lane & 31, kh = lane >> 5;
    int r = tid >> 1, c0 = (tid & 1) << 5;   // 0 or 32

    const ushort_t* sp = (const ushort_t*)Sbase + (size_t)(b * TSEQ + m0 + r) * 4096 + c0;
    const ushort_t* gb = VLT + (size_t)(n0 + r) * BTOT + b * TSEQ + c0;

    f32x16 acc[2][2];
#pragma unroll
    for (int i = 0; i < 2; ++i)
#pragma unroll
        for (int j = 0; j < 2; ++j)
#pragma unroll
            for (int t = 0; t < 16; ++t) acc[i][j][t] = 0.f;

    for (int k0 = 0; k0 < TSEQ; k0 += 64) {
        u16x8 a0 = *(const u16x8*)(sp + k0);
        u16x8 a1 = *(const u16x8*)(sp + k0 + 8);
        u16x8 a2 = *(const u16x8*)(sp + k0 + 16);
        u16x8 a3 = *(const u16x8*)(sp + k0 + 24);
        u16x8 vb0 = *(const u16x8*)(gb + k0);
        u16x8 vb1 = *(const u16x8*)(gb + k0 + 8);
        u16x8 vb2 = *(const u16x8*)(gb + k0 + 16);
        u16x8 vb3 = *(const u16x8*)(gb + k0 + 24);
        __syncthreads();
        *(u16x8*)&As[r][c0]      = a0;  *(u16x8*)&As[r][c0 + 8]  = a1;
        *(u16x8*)&As[r][c0 + 16] = a2;  *(u16x8*)&As[r][c0 + 24] = a3;
        *(u16x8*)&Bs[r][c0]      = vb0; *(u16x8*)&Bs[r][c0 + 8]  = vb1;
        *(u16x8*)&Bs[r][c0 + 16] = vb2; *(u16x8*)&Bs[r][c0 + 24] = vb3;
        __syncthreads();
#pragma unroll
        for (int kc = 0; kc < 4; ++kc) {
            int ka = kc * 16 + kh * 8;
            bf16x8 fa[2], fb[2];
#pragma unroll
            for (int mt = 0; mt < 2; ++mt) {
                fa[mt] = *(const bf16x8*)&As[wm * 64 + mt * 32 + l32][ka];
                fb[mt] = *(const bf16x8*)&Bs[wn * 64 + mt * 32 + l32][ka];
            }
#pragma unroll
            for (int mt = 0; mt < 2; ++mt)
#pragma unroll
                for (int nt = 0; nt < 2; ++nt)
                    acc[mt][nt] = __builtin_amdgcn_mfma_f32_32x32x16_bf16(fa[mt], fb[nt], acc[mt][nt], 0, 0, 0);
        }
    }
    float dsum[2] = {0.f, 0.f};
#pragma unroll
    for (int mt = 0; mt < 2; ++mt)
#pragma unroll
        for (int nt = 0; nt < 2; ++nt) {
            f32x16 c = acc[mt][nt];
            float bias = bias_s[wn * 64 + nt * 32 + l32];
#pragma unroll
            for (int rr = 0; rr < 16; ++rr) {
                int row = wm * 64 + mt * 32 + (rr & 3) + 8 * (rr >> 2) + 4 * kh;
                float v = fmaf(c[rr], linv_s[row], bias);
                dsum[nt] += fmaxf(v, 0.f);
            }
        }
#pragma unroll
    for (int nt = 0; nt < 2; ++nt) {
        float v = dsum[nt];
        v += __shfl_xor(v, 32);
        if (kh == 0) atomicAdd(&accg[b * DIM + n0 + wn * 64 + nt * 32 + l32], v);
    }
}

// ---------------------------------------------------------------------------
// K6: out[b] = sigmoid((accg[b]/T) . clf_w + clf_b)
// ---------------------------------------------------------------------------
__global__ void k_final(const float* __restrict__ accg,
                        const float* __restrict__ clf_w,
                        const float* __restrict__ clf_b,
                        float* __restrict__ out) {
    int tid  = threadIdx.x;
    int b    = tid >> 6;
    int lane = tid & 63;
    float s = 0.f;
    for (int d = lane; d < DIM; d += 64) s = fmaf(accg[b * DIM + d], clf_w[d], s);
#pragma unroll
    for (int off = 32; off > 0; off >>= 1) s += __shfl_xor(s, off);
    if (lane == 0) {
        float z = s * (1.0f / TSEQ) + clf_b[0];
        out[b] = 1.f / (1.f + __expf(-z));
    }
}

// ---------------------------------------------------------------------------
extern "C" void kernel_launch(void* const* d_in, const int* in_sizes, int n_in,
                              void* d_out, int out_size, void* d_ws, size_t ws_size,
                              hipStream_t stream) {
    const int*   x     = (const int*)d_in[0];
    const float* embed = (const float*)d_in[1];
    const float* Wq    = (const float*)d_in[2];
    const float* Wk    = (const float*)d_in[3];
    const float* Wv    = (const float*)d_in[4];
    const float* lin_w = (const float*)d_in[5];
    const float* lin_b = (const float*)d_in[6];
    const float* clf_w = (const float*)d_in[7];
    const float* clf_b = (const float*)d_in[8];
    float* out = (float*)d_out;

    char* wsb = (char*)d_ws;
    float* S = (float*)wsb;                                  // 134 MB, P aliased in
    char* p = wsb + (size_t)NB * TSEQ * TSEQ * 4;
    ushort_t* Ehi  = (ushort_t*)p;
    ushort_t* Elo  = Ehi  + (size_t)BTOT * DIM;
    ushort_t* Hhi  = Elo  + (size_t)BTOT * DIM;
    ushort_t* Hlo  = Hhi  + (size_t)BTOT * DIM;
    ushort_t* VLT  = Hlo  + (size_t)BTOT * DIM;
    ushort_t* Gthi = VLT  + (size_t)DIM * BTOT;
    ushort_t* Gtlo = Gthi + (size_t)DIM * DIM;
    ushort_t* Mbf  = Gtlo + (size_t)DIM * DIM;
    float* linv = (float*)(Mbf + (size_t)DIM * DIM);
    float* accg = linv + BTOT;

    hipMemsetAsync(accg, 0, NB * DIM * sizeof(float), stream);
    k_split_embed<<<BTOT * 64 / 256, 256, 0, stream>>>(x, embed, Ehi, Elo);
    k_wgemm<<<dim3(16, 16, 2), 256, 0, stream>>>(Wq, Wk, lin_w, Wv, Gthi, Gtlo, Mbf);
    k_proj_h<<<dim3(128, 4), 256, 0, stream>>>(Ehi, Elo, Gthi, Gtlo, Hhi, Hlo);
    k_proj_vlt<<<dim3(4, 128), 256, 0, stream>>>(Mbf, Ehi, VLT);
    k_scores<<<dim3(16, 16, 8), 256, 0, stream>>>(Hhi, Hlo, Ehi, Elo, S);
    k_softexp<<<BTOT, 256, 0, stream>>>(S, linv);
    k_pv<<<dim3(16, 4, 8), 256, 0, stream>>>(S, VLT, linv, lin_b, accg);
    k_final<<<1, 512, 0, stream>>>(accg, clf_w, clf_b, out);
}